// Round 6
// baseline (81.380 us; speedup 1.0000x reference)
//
#include <hip/hip_runtime.h>
#include <hip/hip_fp16.h>
#include <math.h>

#define NROWS 4096
#define LMAX 256
#define KDIM 256
#define NREL 50000
#define NCELL 8                      // K-chunks == XCDs; 32 cols (64B fp16) each

#define TBR_ELEMS ((size_t)NCELL * NREL * 32)            // fp16 elements
#define TBR_BYTES (TBR_ELEMS * 2)                        // 25,600,000
#define META_BYTES ((size_t)NROWS * LMAX * 4)            // 4,194,304
#define ROWS_PER_BLK 64

typedef float f32x4 __attribute__((ext_vector_type(4)));

// ---------- Kernel A: XCD-affine convert: cell c handles table cols --------
// [32c, 32c+32) only -> dirty tBR lines land in cell c's (local) L2.
// fp32 source read nontemporally so it doesn't evict the tBR we just wrote.
__global__ __launch_bounds__(256) void convert_kernel(
    const float* __restrict__ table, __half* __restrict__ tBR)
{
    const int cell = blockIdx.x & 7;                      // -> XCD (RR)
    const int rg   = blockIdx.x >> 3;
    const int r    = rg * ROWS_PER_BLK + (threadIdx.x >> 2);
    if (r >= NREL) return;
    const int q    = threadIdx.x & 3;                     // 8-col quarter

    const f32x4* src =
        (const f32x4*)&table[(size_t)r * KDIM + cell * 32 + q * 8];
    const f32x4 f0 = __builtin_nontemporal_load(src);
    const f32x4 f1 = __builtin_nontemporal_load(src + 1);
    __half2 h[4];
    h[0] = __floats2half2_rn(f0.x, f0.y);
    h[1] = __floats2half2_rn(f0.z, f0.w);
    h[2] = __floats2half2_rn(f1.x, f1.y);
    h[3] = __floats2half2_rn(f1.z, f1.w);
    __half* dst = tBR + ((size_t)cell * NREL + r) * 32 + q * 8;
    *(uint4*)dst = *(const uint4*)h;                      // keep in local L2
}

// ---------- Kernel B: masked softmax -> meta (idx<<16 | fp16(w)); zero out -
// All global traffic nontemporal: streamed once, must not evict tBR.
__global__ __launch_bounds__(256) void pass1_softmax(
    const float* __restrict__ w1,
    const float* __restrict__ w2,
    const int*   __restrict__ neigh_idx,
    const int*   __restrict__ lengths,
    unsigned*    __restrict__ meta,
    float*       __restrict__ out)
{
    const int n   = blockIdx.x;
    const int tid = threadIdx.x;

    __shared__ float s_red[4];
    __shared__ float s_b;

    const int len = lengths[n];

    float v = -INFINITY;
    if (tid < len) {
        const float a = __builtin_nontemporal_load(&w1[(size_t)n * LMAX + tid]);
        const float b = __builtin_nontemporal_load(&w2[(size_t)n * LMAX + tid]);
        v = a + b;
    }
    const int idx = __builtin_nontemporal_load(&neigh_idx[(size_t)n * LMAX + tid]);

    float m = v;
    #pragma unroll
    for (int off = 32; off >= 1; off >>= 1)
        m = fmaxf(m, __shfl_down(m, off, 64));
    if ((tid & 63) == 0) s_red[tid >> 6] = m;
    __syncthreads();
    if (tid == 0)
        s_b = fmaxf(fmaxf(s_red[0], s_red[1]), fmaxf(s_red[2], s_red[3]));
    __syncthreads();
    m = s_b;

    const float e = (tid < len) ? __expf(v - m) : 0.0f;
    float s = e;
    #pragma unroll
    for (int off = 32; off >= 1; off >>= 1)
        s += __shfl_down(s, off, 64);
    if ((tid & 63) == 0) s_red[tid >> 6] = s;
    __syncthreads();
    if (tid == 0) s_b = s_red[0] + s_red[1] + s_red[2] + s_red[3];
    __syncthreads();

    const float w = e * (1.0f / s_b);                      // 0 for tid >= len
    const unsigned wb = (unsigned)__half_as_ushort(__float2half_rn(w));
    __builtin_nontemporal_store(((unsigned)idx << 16) | wb,
                                &meta[(size_t)n * LMAX + tid]);

    if (tid == 0) out[n] = 0.0f;
}

// ---------- Kernel C: gather-dot, 1 wave = (n, cell, 128-pair strip) -------
// MLP=8: 8 meta lines (nontemporal) + 8 independent 64B gathers issued before
// any consume (sched_barrier). Candidate fragment from tBR (fp16, local L2).
#define CONSUME(t, mm) do {                                                  \
    const __half2* th_ = (const __half2*)&(t);                               \
    const float2 f0_ = __half22float2(th_[0]);                               \
    const float2 f1_ = __half22float2(th_[1]);                               \
    const float2 f2_ = __half22float2(th_[2]);                               \
    const float2 f3_ = __half22float2(th_[3]);                               \
    float s_ = f0_.x * c0;                                                   \
    s_ = fmaf(f0_.y, c1, s_); s_ = fmaf(f1_.x, c2, s_);                      \
    s_ = fmaf(f1_.y, c3, s_); s_ = fmaf(f2_.x, c4, s_);                      \
    s_ = fmaf(f2_.y, c5, s_); s_ = fmaf(f3_.x, c6, s_);                      \
    s_ = fmaf(f3_.y, c7, s_);                                                \
    const float w_ = __half2float(__ushort_as_half(                          \
        (unsigned short)((mm) & 0xffffu)));                                  \
    acc = fmaf(w_, s_, acc);                                                 \
} while (0)

__global__ __launch_bounds__(256) void gather_kernel(
    const __half*   __restrict__ tBR,
    const int*      __restrict__ cand_idx,
    const int*      __restrict__ lengths,
    const unsigned* __restrict__ meta,
    float*          __restrict__ out)
{
    const int cell = blockIdx.x & 7;                       // -> XCD (RR)
    const int gh   = blockIdx.x >> 3;                      // ngroup*2 + half
    const int half = gh & 1;
    const int n    = (gh >> 1) * 4 + (threadIdx.x >> 6);
    const int lane = threadIdx.x & 63;
    const int slot = lane >> 2;                            // pair slot 0..15
    const int q    = lane & 3;                             // 8-col quarter

    const int len   = lengths[n];
    const int len16 = (len + 15) & ~15;                    // 16..256
    const int base  = half << 7;                           // 0 or 128
    int nk = (len16 - base) >> 4;                          // sub-iters here
    if (nk <= 0) return;                                   // wave-uniform
    if (nk > 8) nk = 8;

    const __half* gbase = tBR + (size_t)cell * NREL * 32 + q * 8;

    // candidate fragment from tBR (fp16, local L2)
    float c0, c1, c2, c3, c4, c5, c6, c7;
    {
        const uint4 cc = *(const uint4*)(gbase + (size_t)cand_idx[n] * 32);
        const __half2* ch = (const __half2*)&cc;
        const float2 x0 = __half22float2(ch[0]);
        const float2 x1 = __half22float2(ch[1]);
        const float2 x2 = __half22float2(ch[2]);
        const float2 x3 = __half22float2(ch[3]);
        c0 = x0.x; c1 = x0.y; c2 = x1.x; c3 = x1.y;
        c4 = x2.x; c5 = x2.y; c6 = x3.x; c7 = x3.y;
    }

    const unsigned* mrow = meta + (size_t)n * LMAX + base + slot;

    // ---- load cluster: 8 meta (nt) + 8 gathers, all guards wave-uniform ---
    unsigned m0 = 0, m1 = 0, m2 = 0, m3 = 0, m4 = 0, m5 = 0, m6 = 0, m7 = 0;
    uint4 t0, t1, t2, t3, t4, t5, t6, t7;

    m0 = __builtin_nontemporal_load(mrow);
    if (nk > 1) m1 = __builtin_nontemporal_load(mrow + 16);
    if (nk > 2) m2 = __builtin_nontemporal_load(mrow + 32);
    if (nk > 3) m3 = __builtin_nontemporal_load(mrow + 48);
    if (nk > 4) m4 = __builtin_nontemporal_load(mrow + 64);
    if (nk > 5) m5 = __builtin_nontemporal_load(mrow + 80);
    if (nk > 6) m6 = __builtin_nontemporal_load(mrow + 96);
    if (nk > 7) m7 = __builtin_nontemporal_load(mrow + 112);

    t0 = *(const uint4*)(gbase + (size_t)(m0 >> 16) * 32);
    if (nk > 1) t1 = *(const uint4*)(gbase + (size_t)(m1 >> 16) * 32);
    if (nk > 2) t2 = *(const uint4*)(gbase + (size_t)(m2 >> 16) * 32);
    if (nk > 3) t3 = *(const uint4*)(gbase + (size_t)(m3 >> 16) * 32);
    if (nk > 4) t4 = *(const uint4*)(gbase + (size_t)(m4 >> 16) * 32);
    if (nk > 5) t5 = *(const uint4*)(gbase + (size_t)(m5 >> 16) * 32);
    if (nk > 6) t6 = *(const uint4*)(gbase + (size_t)(m6 >> 16) * 32);
    if (nk > 7) t7 = *(const uint4*)(gbase + (size_t)(m7 >> 16) * 32);

    __builtin_amdgcn_sched_barrier(0);   // no consume may move above loads

    // ---- consume cluster --------------------------------------------------
    float acc = 0.0f;
    CONSUME(t0, m0);
    if (nk > 1) CONSUME(t1, m1);
    if (nk > 2) CONSUME(t2, m2);
    if (nk > 3) CONSUME(t3, m3);
    if (nk > 4) CONSUME(t4, m4);
    if (nk > 5) CONSUME(t5, m5);
    if (nk > 6) CONSUME(t6, m6);
    if (nk > 7) CONSUME(t7, m7);

    #pragma unroll
    for (int off = 32; off >= 1; off >>= 1)
        acc += __shfl_down(acc, off, 64);
    if (lane == 0) atomicAdd(&out[n], acc);
}

// ---------- Fallback (R1 kernel) if ws too small ---------------------------
__global__ __launch_bounds__(256) void epanre_fallback(
    const float* __restrict__ table,
    const float* __restrict__ w1,
    const float* __restrict__ w2,
    const int*   __restrict__ cand_idx,
    const int*   __restrict__ neigh_idx,
    const int*   __restrict__ lengths,
    float*       __restrict__ out)
{
    const int n   = blockIdx.x;
    const int tid = threadIdx.x;

    __shared__ __align__(16) float s_w[LMAX];
    __shared__ int   s_idx[LMAX];
    __shared__ __align__(16) float s_cand[KDIM];
    __shared__ float s_red[4];
    __shared__ float s_bcast;

    const int len = lengths[n];

    float v = -INFINITY;
    if (tid < len) v = w1[(size_t)n * LMAX + tid] + w2[(size_t)n * LMAX + tid];
    s_idx[tid]  = neigh_idx[(size_t)n * LMAX + tid];
    s_cand[tid] = table[(size_t)cand_idx[n] * KDIM + tid];

    float m = v;
    #pragma unroll
    for (int off = 32; off >= 1; off >>= 1)
        m = fmaxf(m, __shfl_down(m, off, 64));
    if ((tid & 63) == 0) s_red[tid >> 6] = m;
    __syncthreads();
    if (tid == 0)
        s_bcast = fmaxf(fmaxf(s_red[0], s_red[1]), fmaxf(s_red[2], s_red[3]));
    __syncthreads();
    m = s_bcast;

    float e = (tid < len) ? __expf(v - m) : 0.0f;
    float s = e;
    #pragma unroll
    for (int off = 32; off >= 1; off >>= 1)
        s += __shfl_down(s, off, 64);
    if ((tid & 63) == 0) s_red[tid >> 6] = s;
    __syncthreads();
    if (tid == 0) s_bcast = s_red[0] + s_red[1] + s_red[2] + s_red[3];
    __syncthreads();
    const float inv = 1.0f / s_bcast;
    s_w[tid] = e * inv;
    __syncthreads();

    const int g    = tid >> 6;
    const int lane = tid & 63;
    const float4* tab4 = (const float4*)table;
    float4 acc = make_float4(0.f, 0.f, 0.f, 0.f);

    for (int l0 = 0; l0 < len; l0 += 4) {
        const int   l = l0 + g;
        const float w = (l < len) ? s_w[l] : 0.0f;
        const int   idx = s_idx[l];
        const float4 t = tab4[(size_t)idx * (KDIM / 4) + lane];
        acc.x = fmaf(w, t.x, acc.x);
        acc.y = fmaf(w, t.y, acc.y);
        acc.z = fmaf(w, t.z, acc.z);
        acc.w = fmaf(w, t.w, acc.w);
    }

    const float4 c = ((const float4*)s_cand)[lane];
    float partial = acc.x * c.x + acc.y * c.y + acc.z * c.z + acc.w * c.w;
    #pragma unroll
    for (int off = 32; off >= 1; off >>= 1)
        partial += __shfl_down(partial, off, 64);
    if (lane == 0) s_red[g] = partial;
    __syncthreads();
    if (tid == 0) out[n] = s_red[0] + s_red[1] + s_red[2] + s_red[3];
}

extern "C" void kernel_launch(void* const* d_in, const int* in_sizes, int n_in,
                              void* d_out, int out_size, void* d_ws, size_t ws_size,
                              hipStream_t stream) {
    const float* table     = (const float*)d_in[0];
    const float* w1        = (const float*)d_in[1];
    const float* w2        = (const float*)d_in[2];
    const int*   cand_idx  = (const int*)d_in[3];
    const int*   neigh_idx = (const int*)d_in[4];
    const int*   lengths   = (const int*)d_in[5];
    float* out = (float*)d_out;

    if (ws_size < TBR_BYTES + META_BYTES) {
        epanre_fallback<<<NROWS, 256, 0, stream>>>(table, w1, w2, cand_idx,
                                                   neigh_idx, lengths, out);
        return;
    }

    __half*   tBR  = (__half*)d_ws;
    unsigned* meta = (unsigned*)((char*)d_ws + TBR_BYTES);

    const int rgs = (NREL + ROWS_PER_BLK - 1) / ROWS_PER_BLK;   // 782
    convert_kernel<<<rgs * NCELL, 256, 0, stream>>>(table, tBR);
    pass1_softmax<<<NROWS, 256, 0, stream>>>(w1, w2, neigh_idx, lengths,
                                             meta, out);
    // grid: (ngroup, half) x cell; cell in low 3 bits preserves XCD affinity
    gather_kernel<<<(NROWS / 4) * 2 * NCELL, 256, 0, stream>>>(tBR, cand_idx,
                                                               lengths, meta,
                                                               out);
}

// Round 7
// 60.496 us; speedup vs baseline: 1.3452x; 1.3452x over previous
//
#include <hip/hip_runtime.h>
#include <hip/hip_fp16.h>
#include <math.h>

#define NROWS 4096
#define LMAX 256
#define KDIM 256
#define NREL 50000
#define NCELL 8                      // K-chunks == XCDs; 32 cols (64B fp16) each

#define TBR_ELEMS ((size_t)NCELL * NREL * 32)            // fp16 elements
#define TBR_BYTES (TBR_ELEMS * 2)                        // 25,600,000
#define META_BYTES ((size_t)NROWS * LMAX * 4)            // 4,194,304
#define ROWS_PER_BLK 64

typedef float f32x4 __attribute__((ext_vector_type(4)));

// ---------- Kernel A: XCD-affine convert: cell c handles table cols --------
// [32c, 32c+32) only -> dirty tBR lines land in cell c's (local) L2.
__global__ __launch_bounds__(256) void convert_kernel(
    const float* __restrict__ table, __half* __restrict__ tBR)
{
    const int cell = blockIdx.x & 7;                      // -> XCD (RR)
    const int rg   = blockIdx.x >> 3;
    const int r    = rg * ROWS_PER_BLK + (threadIdx.x >> 2);
    if (r >= NREL) return;
    const int q    = threadIdx.x & 3;                     // 8-col quarter

    const f32x4* src =
        (const f32x4*)&table[(size_t)r * KDIM + cell * 32 + q * 8];
    const f32x4 f0 = __builtin_nontemporal_load(src);
    const f32x4 f1 = __builtin_nontemporal_load(src + 1);
    __half2 h[4];
    h[0] = __floats2half2_rn(f0.x, f0.y);
    h[1] = __floats2half2_rn(f0.z, f0.w);
    h[2] = __floats2half2_rn(f1.x, f1.y);
    h[3] = __floats2half2_rn(f1.z, f1.w);
    __half* dst = tBR + ((size_t)cell * NREL + r) * 32 + q * 8;
    *(uint4*)dst = *(const uint4*)h;                      // keep in local L2
}

// ---------- Kernel B: masked softmax -> meta (idx<<16 | fp16(w)) -----------
// Pad slots (tid >= len) write 0: idx=0 (hot row-0 gather), w=0.
__global__ __launch_bounds__(256) void pass1_softmax(
    const float* __restrict__ w1,
    const float* __restrict__ w2,
    const int*   __restrict__ neigh_idx,
    const int*   __restrict__ lengths,
    unsigned*    __restrict__ meta,
    float*       __restrict__ out)
{
    const int n   = blockIdx.x;
    const int tid = threadIdx.x;

    __shared__ float s_red[4];
    __shared__ float s_b;

    const int len = lengths[n];

    float v = -INFINITY;
    if (tid < len) {
        const float a = __builtin_nontemporal_load(&w1[(size_t)n * LMAX + tid]);
        const float b = __builtin_nontemporal_load(&w2[(size_t)n * LMAX + tid]);
        v = a + b;
    }
    const int idx = __builtin_nontemporal_load(&neigh_idx[(size_t)n * LMAX + tid]);

    float m = v;
    #pragma unroll
    for (int off = 32; off >= 1; off >>= 1)
        m = fmaxf(m, __shfl_down(m, off, 64));
    if ((tid & 63) == 0) s_red[tid >> 6] = m;
    __syncthreads();
    if (tid == 0)
        s_b = fmaxf(fmaxf(s_red[0], s_red[1]), fmaxf(s_red[2], s_red[3]));
    __syncthreads();
    m = s_b;

    const float e = (tid < len) ? __expf(v - m) : 0.0f;
    float s = e;
    #pragma unroll
    for (int off = 32; off >= 1; off >>= 1)
        s += __shfl_down(s, off, 64);
    if ((tid & 63) == 0) s_red[tid >> 6] = s;
    __syncthreads();
    if (tid == 0) s_b = s_red[0] + s_red[1] + s_red[2] + s_red[3];
    __syncthreads();

    const float w = e * (1.0f / s_b);
    const unsigned wb = (unsigned)__half_as_ushort(__float2half_rn(w));
    const unsigned mv = (tid < len) ? (((unsigned)idx << 16) | wb) : 0u;
    __builtin_nontemporal_store(mv, &meta[(size_t)n * LMAX + tid]);

    if (tid == 0) out[n] = 0.0f;
}

// ---------- Kernel C: gather-dot, branchless 8-deep load clusters ----------
#define CONSUME(t, mm) do {                                                  \
    const __half2* th_ = (const __half2*)&(t);                               \
    const float2 f0_ = __half22float2(th_[0]);                               \
    const float2 f1_ = __half22float2(th_[1]);                               \
    const float2 f2_ = __half22float2(th_[2]);                               \
    const float2 f3_ = __half22float2(th_[3]);                               \
    float s_ = f0_.x * c0;                                                   \
    s_ = fmaf(f0_.y, c1, s_); s_ = fmaf(f1_.x, c2, s_);                      \
    s_ = fmaf(f1_.y, c3, s_); s_ = fmaf(f2_.x, c4, s_);                      \
    s_ = fmaf(f2_.y, c5, s_); s_ = fmaf(f3_.x, c6, s_);                      \
    s_ = fmaf(f3_.y, c7, s_);                                                \
    const float w_ = __half2float(__ushort_as_half(                          \
        (unsigned short)((mm) & 0xffffu)));                                  \
    acc = fmaf(w_, s_, acc);                                                 \
} while (0)

// One 128-pair cluster: 8 LDS meta reads + 8 independent 64B gathers issued
// before ANY consume (single basic block + sched_barrier -> real MLP=8).
#define CLUSTER8(B) do {                                                     \
    const unsigned m0 = sm[(B)       + slot];                                \
    const unsigned m1 = sm[(B) +  16 + slot];                                \
    const unsigned m2 = sm[(B) +  32 + slot];                                \
    const unsigned m3 = sm[(B) +  48 + slot];                                \
    const unsigned m4 = sm[(B) +  64 + slot];                                \
    const unsigned m5 = sm[(B) +  80 + slot];                                \
    const unsigned m6 = sm[(B) +  96 + slot];                                \
    const unsigned m7 = sm[(B) + 112 + slot];                                \
    const uint4 t0 = *(const uint4*)(gbase + (size_t)(m0 >> 16) * 32);       \
    const uint4 t1 = *(const uint4*)(gbase + (size_t)(m1 >> 16) * 32);       \
    const uint4 t2 = *(const uint4*)(gbase + (size_t)(m2 >> 16) * 32);       \
    const uint4 t3 = *(const uint4*)(gbase + (size_t)(m3 >> 16) * 32);       \
    const uint4 t4 = *(const uint4*)(gbase + (size_t)(m4 >> 16) * 32);       \
    const uint4 t5 = *(const uint4*)(gbase + (size_t)(m5 >> 16) * 32);       \
    const uint4 t6 = *(const uint4*)(gbase + (size_t)(m6 >> 16) * 32);       \
    const uint4 t7 = *(const uint4*)(gbase + (size_t)(m7 >> 16) * 32);       \
    __builtin_amdgcn_sched_barrier(0);                                       \
    CONSUME(t0, m0); CONSUME(t1, m1); CONSUME(t2, m2); CONSUME(t3, m3);      \
    CONSUME(t4, m4); CONSUME(t5, m5); CONSUME(t6, m6); CONSUME(t7, m7);      \
} while (0)

__global__ __launch_bounds__(256) void gather_kernel(
    const __half*   __restrict__ tBR,
    const int*      __restrict__ cand_idx,
    const int*      __restrict__ lengths,
    const unsigned* __restrict__ meta,
    float*          __restrict__ out)
{
    const int cell = blockIdx.x & 7;                       // -> XCD (RR)
    const int wv   = threadIdx.x >> 6;
    const int n    = (blockIdx.x >> 3) * 4 + wv;
    const int lane = threadIdx.x & 63;
    const int slot = lane >> 2;                            // pair slot 0..15
    const int q    = lane & 3;                             // 8-col quarter
    const int len  = lengths[n];

    __shared__ unsigned s_meta[4][LMAX];

    // stage this wave's meta row (1KB); same-wave use only -> no barrier
    *(uint4*)&s_meta[wv][lane * 4] =
        *(const uint4*)&meta[(size_t)n * LMAX + lane * 4];

    const __half* gbase = tBR + (size_t)cell * NREL * 32 + q * 8;

    // candidate fragment from tBR (fp16, local L2)
    float c0, c1, c2, c3, c4, c5, c6, c7;
    {
        const uint4 cc = *(const uint4*)(gbase + (size_t)cand_idx[n] * 32);
        const __half2* ch = (const __half2*)&cc;
        const float2 x0 = __half22float2(ch[0]);
        const float2 x1 = __half22float2(ch[1]);
        const float2 x2 = __half22float2(ch[2]);
        const float2 x3 = __half22float2(ch[3]);
        c0 = x0.x; c1 = x0.y; c2 = x1.x; c3 = x1.y;
        c4 = x2.x; c5 = x2.y; c6 = x3.x; c7 = x3.y;
    }

    const unsigned* sm = s_meta[wv];
    float acc = 0.0f;

    CLUSTER8(0);                       // pairs 0..127 (pads hit row 0, w=0)
    if (len > 128) CLUSTER8(128);      // pairs 128..255, wave-uniform branch

    #pragma unroll
    for (int off = 32; off >= 1; off >>= 1)
        acc += __shfl_down(acc, off, 64);
    if (lane == 0) atomicAdd(&out[n], acc);
}

// ---------- Fallback (R1 kernel) if ws too small ---------------------------
__global__ __launch_bounds__(256) void epanre_fallback(
    const float* __restrict__ table,
    const float* __restrict__ w1,
    const float* __restrict__ w2,
    const int*   __restrict__ cand_idx,
    const int*   __restrict__ neigh_idx,
    const int*   __restrict__ lengths,
    float*       __restrict__ out)
{
    const int n   = blockIdx.x;
    const int tid = threadIdx.x;

    __shared__ __align__(16) float s_w[LMAX];
    __shared__ int   s_idx[LMAX];
    __shared__ __align__(16) float s_cand[KDIM];
    __shared__ float s_red[4];
    __shared__ float s_bcast;

    const int len = lengths[n];

    float v = -INFINITY;
    if (tid < len) v = w1[(size_t)n * LMAX + tid] + w2[(size_t)n * LMAX + tid];
    s_idx[tid]  = neigh_idx[(size_t)n * LMAX + tid];
    s_cand[tid] = table[(size_t)cand_idx[n] * KDIM + tid];

    float m = v;
    #pragma unroll
    for (int off = 32; off >= 1; off >>= 1)
        m = fmaxf(m, __shfl_down(m, off, 64));
    if ((tid & 63) == 0) s_red[tid >> 6] = m;
    __syncthreads();
    if (tid == 0)
        s_bcast = fmaxf(fmaxf(s_red[0], s_red[1]), fmaxf(s_red[2], s_red[3]));
    __syncthreads();
    m = s_bcast;

    float e = (tid < len) ? __expf(v - m) : 0.0f;
    float s = e;
    #pragma unroll
    for (int off = 32; off >= 1; off >>= 1)
        s += __shfl_down(s, off, 64);
    if ((tid & 63) == 0) s_red[tid >> 6] = s;
    __syncthreads();
    if (tid == 0) s_bcast = s_red[0] + s_red[1] + s_red[2] + s_red[3];
    __syncthreads();
    const float inv = 1.0f / s_bcast;
    s_w[tid] = e * inv;
    __syncthreads();

    const int g    = tid >> 6;
    const int lane = tid & 63;
    const float4* tab4 = (const float4*)table;
    float4 acc = make_float4(0.f, 0.f, 0.f, 0.f);

    for (int l0 = 0; l0 < len; l0 += 4) {
        const int   l = l0 + g;
        const float w = (l < len) ? s_w[l] : 0.0f;
        const int   idx = s_idx[l];
        const float4 t = tab4[(size_t)idx * (KDIM / 4) + lane];
        acc.x = fmaf(w, t.x, acc.x);
        acc.y = fmaf(w, t.y, acc.y);
        acc.z = fmaf(w, t.z, acc.z);
        acc.w = fmaf(w, t.w, acc.w);
    }

    const float4 c = ((const float4*)s_cand)[lane];
    float partial = acc.x * c.x + acc.y * c.y + acc.z * c.z + acc.w * c.w;
    #pragma unroll
    for (int off = 32; off >= 1; off >>= 1)
        partial += __shfl_down(partial, off, 64);
    if (lane == 0) s_red[g] = partial;
    __syncthreads();
    if (tid == 0) out[n] = s_red[0] + s_red[1] + s_red[2] + s_red[3];
}

extern "C" void kernel_launch(void* const* d_in, const int* in_sizes, int n_in,
                              void* d_out, int out_size, void* d_ws, size_t ws_size,
                              hipStream_t stream) {
    const float* table     = (const float*)d_in[0];
    const float* w1        = (const float*)d_in[1];
    const float* w2        = (const float*)d_in[2];
    const int*   cand_idx  = (const int*)d_in[3];
    const int*   neigh_idx = (const int*)d_in[4];
    const int*   lengths   = (const int*)d_in[5];
    float* out = (float*)d_out;

    if (ws_size < TBR_BYTES + META_BYTES) {
        epanre_fallback<<<NROWS, 256, 0, stream>>>(table, w1, w2, cand_idx,
                                                   neigh_idx, lengths, out);
        return;
    }

    __half*   tBR  = (__half*)d_ws;
    unsigned* meta = (unsigned*)((char*)d_ws + TBR_BYTES);

    const int rgs = (NREL + ROWS_PER_BLK - 1) / ROWS_PER_BLK;   // 782
    convert_kernel<<<rgs * NCELL, 256, 0, stream>>>(table, tBR);
    pass1_softmax<<<NROWS, 256, 0, stream>>>(w1, w2, neigh_idx, lengths,
                                             meta, out);
    gather_kernel<<<(NROWS / 4) * NCELL, 256, 0, stream>>>(tBR, cand_idx,
                                                           lengths, meta,
                                                           out);
}